// Round 5
// baseline (89.292 us; speedup 1.0000x reference)
//
#include <hip/hip_runtime.h>
#include <math.h>

// Problem constants (from reference): B=8, C=32, F=32, K=3, H=W=32
#define NB 8
#define NC 32
#define NF 32
#define NH 32
#define NW 32
#define NQ 9
#define CSPLIT 8            // channel-loop split factor
#define CPB (NC / CSPLIT)   // 4 channels per block

#define PROWS 34            // padded rows
#define PCOLS 36            // padded cols (+2 slack: rows 16B-aligned, dwordx4
                            //  overread at xx=31 stays in-bounds)

// d_ws layout (floats):
//   [0, COEFF_FLOATS)             : coeff records, 12 floats per (f,q,c)
//   [COEFF_FLOATS, +XPAD_FLOATS)  : zero-padded input [B][C][34][36]
#define NREC (NF * NQ * NC)                    // 9216 records
#define COEFF_FLOATS (NREC * 12)               // 110592 (16B-aligned records)
#define XPAD_FLOATS (NB * NC * PROWS * PCOLS)  // 313344

typedef float f4 __attribute__((ext_vector_type(4), aligned(16)));
typedef float f2 __attribute__((ext_vector_type(2)));
__device__ __forceinline__ f2 sp(float v) { return (f2){v, v}; }

// --- prep kernel 1: interleave nums/denoms into 48B records -----------------
// record r=(f*9+q)*32+c : [a0..a3][d0..d3][a4,a5,pad,pad]
__global__ __launch_bounds__(256) void reformat_coeffs(
    const float* __restrict__ nums, const float* __restrict__ dens,
    float* __restrict__ rec)
{
    int r = blockIdx.x * 256 + threadIdx.x;
    if (r >= NREC) return;
    const float* a = nums + (size_t)r * 6;
    const float* d = dens + (size_t)r * 4;
    float* o = rec + (size_t)r * 12;
    o[0] = a[0]; o[1] = a[1]; o[2]  = a[2]; o[3]  = a[3];
    o[4] = d[0]; o[5] = d[1]; o[6]  = d[2]; o[7]  = d[3];
    o[8] = a[4]; o[9] = a[5]; o[10] = 0.f;  o[11] = 0.f;
}

// --- prep kernel 2: zero-padded copy of x -----------------------------------
__global__ __launch_bounds__(256) void prepad_x(
    const float* __restrict__ x, float* __restrict__ xp)
{
    int idx = blockIdx.x * 256 + threadIdx.x; // < XPAD_FLOATS exactly
    int px  = idx % PCOLS;
    int t1  = idx / PCOLS;
    int py  = t1 % PROWS;
    int bc  = t1 / PROWS;
    float v = 0.f;
    if (py >= 1 && py <= NH && px >= 1 && px <= NW)
        v = x[(size_t)bc * NH * NW + (py - 1) * NW + (px - 1)];
    xp[idx] = v;
}

// --- main kernel -------------------------------------------------------------
// Block = 256 threads, 2 vertically-adjacent pixels each (half image).
// Grid = B*F*2*CSPLIT = 4096. NO LDS, NO barriers, NO s_loads in the loop:
// windows AND coefficients ride the vector-memory path (vmcnt), which the
// backend software-pipelines with fine-grained vmcnt(N) waits — unlike SMEM,
// whose out-of-order completion forces unpipelineable lgkmcnt(0) drains.
// Coefficient loads are all-lanes-same-address -> one L1 line + broadcast;
// VOP3P op_sel broadcasts the scalar coeffs into pk math for free.
__global__ __launch_bounds__(256, 6) void ka_conv_rational_kernel(
    const float* __restrict__ cf,   // coeff records [NREC][12]
    const float* __restrict__ xp,   // padded input [B][C][34][36]
    float* __restrict__ out)        // [B, F, H, W] (pre-zeroed)
{
    const int t    = threadIdx.x;
    const int bid  = blockIdx.x;          // 0..4095
    const int cs   = bid & (CSPLIT - 1);  // channel chunk
    const int half = (bid >> 3) & 1;
    const int bf   = bid >> 4;            // b*NF + f
    const int f    = bf & (NF - 1);
    const int bb   = bf >> 5;
    const int xx   = t & 31;              // output col
    const int ty   = t >> 5;              // 0..7
    const int y0   = half * 16 + ty * 2;  // output row of px0 (= padded top row)
    const int c0   = cs * CPB;

    // window base: padded rows y0..y0+3, cols xx..xx+3 (xx..xx+2 used)
    const float* xbase = xp + (((size_t)(bb * NC + c0) * PROWS) + y0) * PCOLS + xx;
    const float* cfp0  = cf + (size_t)(f * NQ * NC + c0) * 12;

    f4 cur[4], nxt[4];
#pragma unroll
    for (int r = 0; r < 4; ++r)
        cur[r] = *(const f4*)(xbase + r * PCOLS);

    f2 acc = {0.f, 0.f};

#pragma unroll
    for (int ci = 0; ci < CPB; ++ci) {
        if (ci + 1 < CPB) {
            const float* xn = xbase + (size_t)(ci + 1) * PROWS * PCOLS;
#pragma unroll
            for (int r = 0; r < 4; ++r)
                nxt[r] = *(const f4*)(xn + r * PCOLS);
        }
        const float* cq = cfp0 + (size_t)ci * 12;

#pragma unroll
        for (int q = 0; q < NQ; ++q) {
            // per-lane vector loads, uniform address -> L1 broadcast
            const f4 k0 = *(const f4*)(cq + (size_t)q * NC * 12);      // a0..a3
            const f4 k1 = *(const f4*)(cq + (size_t)q * NC * 12 + 4);  // d0..d3
            const f4 k2 = *(const f4*)(cq + (size_t)q * NC * 12 + 8);  // a4,a5,-,-
            const int qi = q / 3, qj = q - qi * 3;

            f2 w = {cur[qi][qj], cur[qi + 1][qj]};
            f2 nu = __builtin_elementwise_fma(sp(k2.y), w, sp(k2.x)); // a5*w+a4
            nu = __builtin_elementwise_fma(nu, w, sp(k0.w));
            nu = __builtin_elementwise_fma(nu, w, sp(k0.z));
            nu = __builtin_elementwise_fma(nu, w, sp(k0.y));
            nu = __builtin_elementwise_fma(nu, w, sp(k0.x));
            f2 dp = __builtin_elementwise_fma(sp(k1.w), w, sp(k1.z)); // d3*w+d2
            dp = __builtin_elementwise_fma(dp, w, sp(k1.y));
            dp = __builtin_elementwise_fma(dp, w, sp(k1.x));
            dp = dp * w;
            f2 de = 1.0f + __builtin_elementwise_abs(dp);
            f2 rc = {__builtin_amdgcn_rcpf(de.x), __builtin_amdgcn_rcpf(de.y)};
            acc = __builtin_elementwise_fma(nu, rc, acc);
        }

#pragma unroll
        for (int r = 0; r < 4; ++r)
            cur[r] = nxt[r];
    }

    float* op = out + ((size_t)bf * NH + y0) * NW + xx;
    unsafeAtomicAdd(op,      acc.x);
    unsafeAtomicAdd(op + NW, acc.y);
}

extern "C" void kernel_launch(void* const* d_in, const int* in_sizes, int n_in,
                              void* d_out, int out_size, void* d_ws, size_t ws_size,
                              hipStream_t stream) {
    const float* x    = (const float*)d_in[0];
    const float* nums = (const float*)d_in[1];
    const float* dens = (const float*)d_in[2];
    float* out = (float*)d_out;

    float* cfrec = (float*)d_ws;              // 442368 B (16B-aligned)
    float* xpad  = cfrec + COEFF_FLOATS;

    reformat_coeffs<<<(NREC + 255) / 256, 256, 0, stream>>>(nums, dens, cfrec);
    prepad_x<<<XPAD_FLOATS / 256, 256, 0, stream>>>(x, xpad);

    // atomic accumulation target must start at zero (harness poisons d_out)
    hipMemsetAsync(d_out, 0, (size_t)out_size * sizeof(float), stream);

    dim3 grid(NB * NF * 2 * CSPLIT); // 4096 blocks: (b, f, half, csplit)
    ka_conv_rational_kernel<<<grid, 256, 0, stream>>>(cfrec, xpad, out);
}